// Round 2
// baseline (1333.422 us; speedup 1.0000x reference)
//
#include <hip/hip_runtime.h>

typedef __bf16 bf16x8 __attribute__((ext_vector_type(8)));
typedef __bf16 bf16x4 __attribute__((ext_vector_type(4)));
typedef float  f32x4  __attribute__((ext_vector_type(4)));

#define NTOK 256
#define DIM  128
#define NH   4

// LDS layout (64 KiB):
//  QS [256 tok][32 d] bf16, row 64B, swizzle: col-byte ^= ((t>>1)&3)<<4   : 16384
//  KS same as QS                                                          : 16384
//  VT [32 d][256 tok] bf16, row 512B, swizzle: col-byte ^= ((d&7)<<4)     : 16384
//  PB 8 waves x 2 x 1KiB (P/O staging, double-buffered)                   : 16384
#define QS_OFF 0
#define KS_OFF 16384
#define VT_OFF 32768
#define PB_OFF 49152
#define SMEM_BYTES 65536

// ---------------- prep kernels (run once per launch, tiny) ----------------

// biasT_frag[((h*16+kt)*16+qt)*64+lane][j] = bias[h][q=qt*16+(lane&15)][k=kt*16+(lane>>4)*4+j]
// (S^T fragment layout: row=k-token=4*hi+j, col=q-token=lr)
__global__ void bias_prep(const float* __restrict__ bias_table, float* __restrict__ biasT)
{
    const int g = blockIdx.x * 256 + threadIdx.x;       // 0..65535
    const int lane = g & 63;
    const int tile = g >> 6;                            // ((h*16+kt)*16+qt)
    const int qt = tile & 15, kt = (tile >> 4) & 15, h = tile >> 8;
    const int lr = lane & 15, rg = lane >> 4;
    // idx(q,k) = (rq-rk+15)*31 + (cq-ck+15);  rq=qt, cq=lr, rk=kt, ck=rg*4+j
    const int base = (qt - kt + 15) * 31 + (lr - rg * 4 + 15);
    float4 v;
    v.x = bias_table[(base - 0) * 4 + h];
    v.y = bias_table[(base - 1) * 4 + h];
    v.z = bias_table[(base - 2) * 4 + h];
    v.w = bias_table[(base - 3) * 4 + h];
    *reinterpret_cast<float4*>(biasT + (size_t)g * 4) = v;
}

// qkvT[colg][k] = (bf16)qkv_w[k][colg]   (384 x 128)
// projT[col][k] = (bf16)proj_w[k][col]   (128 x 128)
__global__ void weight_prep(const float* __restrict__ qkv_w, const float* __restrict__ proj_w,
                            __bf16* __restrict__ qkvT, __bf16* __restrict__ projT)
{
    const int g = blockIdx.x * 256 + threadIdx.x;       // 0..65535
    if (g < 49152) {
        const int k = g / 384, colg = g - k * 384;
        qkvT[colg * 128 + k] = (__bf16)qkv_w[g];
    } else {
        const int g2 = g - 49152;
        const int k = g2 >> 7, col = g2 & 127;
        projT[col * 128 + k] = (__bf16)proj_w[g2];
    }
}

// ---------------- fragment-load helpers (table or f32 fallback) ----------------

__device__ __forceinline__ bf16x8 load_w_qkv(const __bf16* qkvT, const float* qkv_w,
                                             int colg, int kbase)
{
    if (qkvT) return *reinterpret_cast<const bf16x8*>(qkvT + colg * 128 + kbase);
    bf16x8 v;
#pragma unroll
    for (int e = 0; e < 8; ++e) v[e] = (__bf16)qkv_w[(kbase + e) * 384 + colg];
    return v;
}

__device__ __forceinline__ bf16x8 load_w_proj(const __bf16* projT, const float* proj_w,
                                              int col, int kbase)
{
    if (projT) return *reinterpret_cast<const bf16x8*>(projT + col * 128 + kbase);
    bf16x8 v;
#pragma unroll
    for (int e = 0; e < 8; ++e) v[e] = (__bf16)proj_w[(kbase + e) * 128 + col];
    return v;
}

// ---------------- main fused kernel ----------------
// All MFMA tiles are computed TRANSPOSED (swap A/B operands) so the C-fragment's
// 4 values are 4 consecutive columns -> packed 8B LDS writes / float4 stores.

template<bool SPLIT>
__global__ __launch_bounds__(512, 4) void attn_main(
    const float* __restrict__ x, const float* __restrict__ noise,
    const float* __restrict__ qkv_w, const float* __restrict__ proj_w,
    const float* __restrict__ proj_b, const float* __restrict__ bias_table,
    const float* __restrict__ nstr, const float* __restrict__ biasT,
    const __bf16* __restrict__ qkvT, const __bf16* __restrict__ projT,
    __bf16* __restrict__ O_ws, float* __restrict__ out)
{
    extern __shared__ char smem[];
    const int b = blockIdx.x, tid = threadIdx.x;
    const int wave = tid >> 6, lane = tid & 63;
    const int lr = lane & 15, hi = lane >> 4;
    const int wrow = wave * 32;

    const float ns = nstr[0];
    const float scale = 0.17677669529663689f;   // 32^-0.5, folded into Q

    // X fragments in regs (noise added, bf16). Serves as A- or B-operand.
    bf16x8 Xf[2][4];
#pragma unroll
    for (int rb = 0; rb < 2; ++rb) {
        const int row = wrow + rb * 16 + lr;
        const float nz = noise[(size_t)b * NTOK + row] * ns;
        const float* prow = x + ((size_t)b * NTOK + row) * DIM;
#pragma unroll
        for (int kc = 0; kc < 4; ++kc) {
            const float4 a0 = *reinterpret_cast<const float4*>(prow + kc * 32 + hi * 8);
            const float4 a1 = *reinterpret_cast<const float4*>(prow + kc * 32 + hi * 8 + 4);
            bf16x8 v;
            v[0] = (__bf16)(a0.x + nz); v[1] = (__bf16)(a0.y + nz);
            v[2] = (__bf16)(a0.z + nz); v[3] = (__bf16)(a0.w + nz);
            v[4] = (__bf16)(a1.x + nz); v[5] = (__bf16)(a1.y + nz);
            v[6] = (__bf16)(a1.z + nz); v[7] = (__bf16)(a1.w + nz);
            Xf[rb][kc] = v;
        }
    }

    bf16x4 obf[4][2][2];   // per-head O^T (bf16), only used when !SPLIT (h,rb unrolled -> static)

#pragma unroll
    for (int h = 0; h < 4; ++h) {
        __syncthreads();   // QS/KS/VT rewrite vs previous head's readers
        // ---- QKV GEMM (transposed): D[wcol][token] = mfma(W^T-frag, X-frag) ----
#pragma unroll
        for (int rb = 0; rb < 2; ++rb) {
            const int t = wrow + rb * 16 + lr;          // token this lane's column holds
            const int tsw = ((t >> 1) & 3) << 4;
#pragma unroll
            for (int ct = 0; ct < 6; ++ct) {
                const int sec = ct >> 1;
                const int colg = sec * 128 + h * 32 + (ct & 1) * 16 + lr;
                f32x4 c = (f32x4){0.f, 0.f, 0.f, 0.f};
#pragma unroll
                for (int kc = 0; kc < 4; ++kc) {
                    const bf16x8 wf = load_w_qkv(qkvT, qkv_w, colg, kc * 32 + hi * 8);
                    c = __builtin_amdgcn_mfma_f32_16x16x32_bf16(wf, Xf[rb][kc], c, 0, 0, 0);
                }
                // c[j] = value for (dloc = (ct&1)*16 + hi*4 + j, token t)
                if (sec == 0) {
                    bf16x4 pk;
#pragma unroll
                    for (int j = 0; j < 4; ++j) pk[j] = (__bf16)(c[j] * scale);
                    *reinterpret_cast<bf16x4*>(smem + QS_OFF + t * 64 +
                        (((ct & 1) * 32 + hi * 8) ^ tsw)) = pk;
                } else if (sec == 1) {
                    bf16x4 pk;
#pragma unroll
                    for (int j = 0; j < 4; ++j) pk[j] = (__bf16)c[j];
                    *reinterpret_cast<bf16x4*>(smem + KS_OFF + t * 64 +
                        (((ct & 1) * 32 + hi * 8) ^ tsw)) = pk;
                } else {
#pragma unroll
                    for (int j = 0; j < 4; ++j) {
                        const int d = (ct & 1) * 16 + hi * 4 + j;
                        *reinterpret_cast<__bf16*>(smem + VT_OFF + d * 512 +
                            ((t * 2) ^ ((d & 7) << 4))) = (__bf16)c[j];
                    }
                }
            }
        }
        __syncthreads();

        // ---- attention (transposed S): lane's column = its q-row = lr ----
#pragma unroll
        for (int rb = 0; rb < 2; ++rb) {
            const int rt = wave * 2 + rb;               // q-token tile
            const int tq = wrow + rb * 16 + lr;
            const int qsw = ((tq >> 1) & 3) << 4;
            const bf16x8 qf = *reinterpret_cast<const bf16x8*>(
                smem + QS_OFF + tq * 64 + ((hi * 16) ^ qsw));

            float lsum = 0.f;
            bf16x4 p16[16];
#pragma unroll
            for (int ct = 0; ct < 16; ++ct) {
                const int tk = ct * 16 + lr;
                const bf16x8 kf = *reinterpret_cast<const bf16x8*>(
                    smem + KS_OFF + tk * 64 + ((hi * 16) ^ (((tk >> 1) & 3) << 4)));
                f32x4 s = __builtin_amdgcn_mfma_f32_16x16x32_bf16(
                    kf, qf, (f32x4){0.f, 0.f, 0.f, 0.f}, 0, 0, 0);
                // s[j] = S[k = ct*16+hi*4+j][q = rt*16+lr]
                if (biasT) {
                    const float4 bv = *reinterpret_cast<const float4*>(
                        biasT + ((((h * 16 + ct) * 16 + rt) * 64 + lane) << 2));
                    s[0] += bv.x; s[1] += bv.y; s[2] += bv.z; s[3] += bv.w;
                } else {
                    const int base0 = (rt - ct + 15) * 31 + (lr - hi * 4 + 15);
#pragma unroll
                    for (int j = 0; j < 4; ++j) s[j] += bias_table[(base0 - j) * 4 + h];
                }
                // |S| << 1 for this problem: exp without max-subtraction is safe
                bf16x4 pk;
#pragma unroll
                for (int j = 0; j < 4; ++j) {
                    const float p = __expf(s[j]);
                    lsum += p;
                    pk[j] = (__bf16)p;
                }
                p16[ct] = pk;
            }
            lsum += __shfl_xor(lsum, 16, 64);
            lsum += __shfl_xor(lsum, 32, 64);
            const float rl = 1.f / lsum;

            // ---- PV (transposed): O^T = mfma(V^T-frag, P-frag) ----
            f32x4 O0 = (f32x4){0.f, 0.f, 0.f, 0.f};
            f32x4 O1 = (f32x4){0.f, 0.f, 0.f, 0.f};
            char* pbase = smem + PB_OFF + wave * 2048;
            const int psw = ((lr >> 1) & 3) << 4;
#pragma unroll
            for (int kcc = 0; kcc < 8; ++kcc) {
                char* pb = pbase + ((kcc & 1) << 10);
                *reinterpret_cast<bf16x4*>(pb + lr * 64 + ((hi * 8) ^ psw))      = p16[2 * kcc];
                *reinterpret_cast<bf16x4*>(pb + lr * 64 + ((32 + hi * 8) ^ psw)) = p16[2 * kcc + 1];
                const bf16x8 pf = *reinterpret_cast<const bf16x8*>(
                    pb + lr * 64 + ((hi * 16) ^ psw));
                const bf16x8 v0 = *reinterpret_cast<const bf16x8*>(
                    smem + VT_OFF + lr * 512 + ((kcc * 64 + hi * 16) ^ ((lr & 7) << 4)));
                const bf16x8 v1 = *reinterpret_cast<const bf16x8*>(
                    smem + VT_OFF + (16 + lr) * 512 + ((kcc * 64 + hi * 16) ^ ((lr & 7) << 4)));
                O0 = __builtin_amdgcn_mfma_f32_16x16x32_bf16(v0, pf, O0, 0, 0, 0);
                O1 = __builtin_amdgcn_mfma_f32_16x16x32_bf16(v1, pf, O1, 0, 0, 0);
            }
            // O^T frag: lane holds O[t=tq][d = {hi*4+j, 16+hi*4+j}]
            if constexpr (SPLIT) {
                bf16x4 oa, ob;
#pragma unroll
                for (int j = 0; j < 4; ++j) {
                    oa[j] = (__bf16)(O0[j] * rl);
                    ob[j] = (__bf16)(O1[j] * rl);
                }
                const size_t rp = ((size_t)b * NTOK + tq) * DIM + h * 32;
                *reinterpret_cast<bf16x4*>(O_ws + rp + hi * 4)      = oa;
                *reinterpret_cast<bf16x4*>(O_ws + rp + 16 + hi * 4) = ob;
            } else {
                bf16x4 oa, ob;
#pragma unroll
                for (int j = 0; j < 4; ++j) {
                    oa[j] = (__bf16)(O0[j] * rl);
                    ob[j] = (__bf16)(O1[j] * rl);
                }
                obf[h][rb][0] = oa;
                obf[h][rb][1] = ob;
            }
        }
    }

    if constexpr (!SPLIT) {
        // fused proj: accT[oc][t] = sum_h mfma(Wp^T-frag, O-frag)
        char* pbase = smem + PB_OFF + wave * 2048;
        const int psw = ((lr >> 1) & 3) << 4;
#pragma unroll
        for (int rb = 0; rb < 2; ++rb) {
            f32x4 acc2[8];
#pragma unroll
            for (int ct = 0; ct < 8; ++ct) acc2[ct] = (f32x4){0.f, 0.f, 0.f, 0.f};
#pragma unroll
            for (int h = 0; h < 4; ++h) {
                char* pb = pbase + ((h & 1) << 10);
                *reinterpret_cast<bf16x4*>(pb + lr * 64 + ((hi * 8) ^ psw))      = obf[h][rb][0];
                *reinterpret_cast<bf16x4*>(pb + lr * 64 + ((32 + hi * 8) ^ psw)) = obf[h][rb][1];
                const bf16x8 of = *reinterpret_cast<const bf16x8*>(
                    pb + lr * 64 + ((hi * 16) ^ psw));
#pragma unroll
                for (int ct = 0; ct < 8; ++ct) {
                    const bf16x8 wpf = load_w_proj(projT, proj_w, ct * 16 + lr, h * 32 + hi * 8);
                    acc2[ct] = __builtin_amdgcn_mfma_f32_16x16x32_bf16(wpf, of, acc2[ct], 0, 0, 0);
                }
            }
            const int tq = wrow + rb * 16 + lr;
#pragma unroll
            for (int ct = 0; ct < 8; ++ct) {
                const float4 pbv = *reinterpret_cast<const float4*>(proj_b + ct * 16 + hi * 4);
                f32x4 st;
                st[0] = acc2[ct][0] + pbv.x; st[1] = acc2[ct][1] + pbv.y;
                st[2] = acc2[ct][2] + pbv.z; st[3] = acc2[ct][3] + pbv.w;
                *reinterpret_cast<f32x4*>(out + ((size_t)b * NTOK + tq) * DIM +
                                          ct * 16 + hi * 4) = st;
            }
        }
    }
}

// ---------------- proj GEMM kernel (SPLIT path) ----------------
// out[t][oc] = O[t][:] @ Wp + b ; transposed tiles -> float4 stores. No LDS.
__global__ __launch_bounds__(256, 4) void proj_kernel(
    const __bf16* __restrict__ O_ws, const __bf16* __restrict__ projT,
    const float* __restrict__ proj_w, const float* __restrict__ proj_b,
    float* __restrict__ out)
{
    const int tid = threadIdx.x;
    const int wave = tid >> 6, lane = tid & 63;
    const int lr = lane & 15, hi = lane >> 4;
    const int row0 = blockIdx.x * 128 + wave * 32;

#pragma unroll
    for (int rb = 0; rb < 2; ++rb) {
        const size_t t = (size_t)row0 + rb * 16 + lr;
        bf16x8 af[4];
#pragma unroll
        for (int kc = 0; kc < 4; ++kc)
            af[kc] = *reinterpret_cast<const bf16x8*>(O_ws + t * DIM + kc * 32 + hi * 8);
#pragma unroll
        for (int ct = 0; ct < 8; ++ct) {
            f32x4 a = (f32x4){0.f, 0.f, 0.f, 0.f};
#pragma unroll
            for (int kc = 0; kc < 4; ++kc) {
                const bf16x8 wpf = load_w_proj(projT, proj_w, ct * 16 + lr, kc * 32 + hi * 8);
                a = __builtin_amdgcn_mfma_f32_16x16x32_bf16(wpf, af[kc], a, 0, 0, 0);
            }
            const float4 pbv = *reinterpret_cast<const float4*>(proj_b + ct * 16 + hi * 4);
            f32x4 st;
            st[0] = a[0] + pbv.x; st[1] = a[1] + pbv.y;
            st[2] = a[2] + pbv.z; st[3] = a[3] + pbv.w;
            *reinterpret_cast<f32x4*>(out + t * DIM + ct * 16 + hi * 4) = st;
        }
    }
}

// ---------------- launcher ----------------

extern "C" void kernel_launch(void* const* d_in, const int* in_sizes, int n_in,
                              void* d_out, int out_size, void* d_ws, size_t ws_size,
                              hipStream_t stream)
{
    const float* x          = (const float*)d_in[0];
    const float* noise      = (const float*)d_in[1];
    const float* qkv_w      = (const float*)d_in[2];
    const float* proj_w     = (const float*)d_in[3];
    const float* proj_b     = (const float*)d_in[4];
    const float* bias_table = (const float*)d_in[5];
    const float* nstr       = (const float*)d_in[6];
    float* out = (float*)d_out;
    (void)in_sizes; (void)n_in; (void)out_size;

    char* ws = (char*)d_ws;
    const size_t OFF_BIAS  = 0;
    const size_t OFF_QKVT  = (size_t)1 << 20;
    const size_t OFF_PROJT = OFF_QKVT + 384 * 128 * 2;
    const size_t OFF_O     = (size_t)2 << 20;
    const size_t NEED_TAB  = OFF_PROJT + 128 * 128 * 2;
    const size_t NEED_FULL = OFF_O + (size_t)1024 * NTOK * DIM * 2;   // +64 MiB O buffer

    const float*  biasT = nullptr;
    const __bf16* qkvT  = nullptr;
    const __bf16* projT = nullptr;
    if (ws_size >= NEED_TAB) {
        bias_prep<<<256, 256, 0, stream>>>(bias_table, (float*)(ws + OFF_BIAS));
        weight_prep<<<256, 256, 0, stream>>>(qkv_w, proj_w,
                                             (__bf16*)(ws + OFF_QKVT), (__bf16*)(ws + OFF_PROJT));
        biasT = (const float*)(ws + OFF_BIAS);
        qkvT  = (const __bf16*)(ws + OFF_QKVT);
        projT = (const __bf16*)(ws + OFF_PROJT);
    }

    if (ws_size >= NEED_FULL && qkvT) {
        hipFuncSetAttribute(reinterpret_cast<const void*>(attn_main<true>),
                            hipFuncAttributeMaxDynamicSharedMemorySize, SMEM_BYTES);
        __bf16* O_ws = (__bf16*)(ws + OFF_O);
        attn_main<true><<<1024, 512, SMEM_BYTES, stream>>>(
            x, noise, qkv_w, proj_w, proj_b, bias_table, nstr,
            biasT, qkvT, projT, O_ws, out);
        proj_kernel<<<2048, 256, 0, stream>>>(O_ws, projT, proj_w, proj_b, out);
    } else {
        hipFuncSetAttribute(reinterpret_cast<const void*>(attn_main<false>),
                            hipFuncAttributeMaxDynamicSharedMemorySize, SMEM_BYTES);
        attn_main<false><<<1024, 512, SMEM_BYTES, stream>>>(
            x, noise, qkv_w, proj_w, proj_b, bias_table, nstr,
            biasT, qkvT, projT, nullptr, out);
    }
}

// Round 3
// 262.215 us; speedup vs baseline: 5.0852x; 5.0852x over previous
//
#include <hip/hip_runtime.h>

typedef __bf16 bf16x8 __attribute__((ext_vector_type(8)));
typedef __bf16 bf16x4 __attribute__((ext_vector_type(4)));
typedef float  f32x4  __attribute__((ext_vector_type(4)));

#define NTOK 256
#define DIM  128

// LDS layout (56 KiB):
//  QS [256 tok][32 d] bf16, row 64B, swizzle: 16B-slot ^= ((t>>1)&3)<<4   : 16384
//  KS same as QS                                                          : 16384
//  VT [32 d][256 tok] bf16, row 512B, swizzle: byte ^= ((d&7)<<4)         : 16384
//  PB 8 waves x 1KiB (P staging, single buffer; per-wave LDS is in-order) :  8192
#define QS_OFF 0
#define KS_OFF 16384
#define VT_OFF 32768
#define PB_OFF 49152
#define SMEM_BYTES 57344

// ---------------- prep kernels (tiny, run once per launch) ----------------

// biasT_frag[((h*16+kt)*16+qt)*64+lane][j] = bias[h][q=qt*16+(lane&15)][k=kt*16+(lane>>4)*4+j]
__global__ void bias_prep(const float* __restrict__ bias_table, float* __restrict__ biasT)
{
    const int g = blockIdx.x * 256 + threadIdx.x;       // 0..65535
    const int lane = g & 63;
    const int tile = g >> 6;                            // ((h*16+kt)*16+qt)
    const int qt = tile & 15, kt = (tile >> 4) & 15, h = tile >> 8;
    const int lr = lane & 15, rg = lane >> 4;
    // idx(q,k) = (rq-rk+15)*31 + (cq-ck+15);  rq=qt, cq=lr, rk=kt, ck=rg*4+j
    const int base = (qt - kt + 15) * 31 + (lr - rg * 4 + 15);
    float4 v;
    v.x = bias_table[(base - 0) * 4 + h];
    v.y = bias_table[(base - 1) * 4 + h];
    v.z = bias_table[(base - 2) * 4 + h];
    v.w = bias_table[(base - 3) * 4 + h];
    *reinterpret_cast<float4*>(biasT + (size_t)g * 4) = v;
}

// qkvT[colg][k] = (bf16)qkv_w[k][colg]   (384 x 128)
// projT[col][k] = (bf16)proj_w[k][col]   (128 x 128)
__global__ void weight_prep(const float* __restrict__ qkv_w, const float* __restrict__ proj_w,
                            __bf16* __restrict__ qkvT, __bf16* __restrict__ projT)
{
    const int g = blockIdx.x * 256 + threadIdx.x;       // 0..65535
    if (g < 49152) {
        const int k = g / 384, colg = g - k * 384;
        qkvT[colg * 128 + k] = (__bf16)qkv_w[g];
    } else {
        const int g2 = g - 49152;
        const int k = g2 >> 7, col = g2 & 127;
        projT[col * 128 + k] = (__bf16)proj_w[g2];
    }
}

// ---------------- attention kernel (QKV + attn, O^T -> O_ws bf16) ----------------
// All MFMA tiles computed TRANSPOSED (swap A/B) so C-frag's 4 values are 4
// consecutive columns -> packed 8B LDS writes / 8B global stores.
// launch_bounds (512,2): cap 256; allocator lands <=128 naturally (R1 evidence)
// -> 4 waves/EU with 2 blocks/CU (LDS 2x56K=112K <= 160K).

__global__ __launch_bounds__(512, 2) void attn_main(
    const float* __restrict__ x, const float* __restrict__ noise,
    const float* __restrict__ nstr, const float* __restrict__ biasT,
    const __bf16* __restrict__ qkvT, __bf16* __restrict__ O_ws)
{
    extern __shared__ char smem[];
    const int b = blockIdx.x, tid = threadIdx.x;
    const int wave = tid >> 6, lane = tid & 63;
    const int lr = lane & 15, hi = lane >> 4;
    const int wrow = wave * 32;

    const float ns    = nstr[0];
    const float scale = 0.17677669529663689f;   // 32^-0.5, folded into Q

    // X fragments in regs (noise added, bf16): B-operand, col=token=lr, k=hi*8+e
    bf16x8 Xf[2][4];
#pragma unroll
    for (int rb = 0; rb < 2; ++rb) {
        const int row = wrow + rb * 16 + lr;
        const float nz = noise[(size_t)b * NTOK + row] * ns;
        const float* prow = x + ((size_t)b * NTOK + row) * DIM;
#pragma unroll
        for (int kc = 0; kc < 4; ++kc) {
            const float4 a0 = *reinterpret_cast<const float4*>(prow + kc * 32 + hi * 8);
            const float4 a1 = *reinterpret_cast<const float4*>(prow + kc * 32 + hi * 8 + 4);
            bf16x8 v;
            v[0] = (__bf16)(a0.x + nz); v[1] = (__bf16)(a0.y + nz);
            v[2] = (__bf16)(a0.z + nz); v[3] = (__bf16)(a0.w + nz);
            v[4] = (__bf16)(a1.x + nz); v[5] = (__bf16)(a1.y + nz);
            v[6] = (__bf16)(a1.z + nz); v[7] = (__bf16)(a1.w + nz);
            Xf[rb][kc] = v;
        }
    }

#pragma unroll 1
    for (int h = 0; h < 4; ++h) {
        __syncthreads();   // QS/KS/VT rewrite vs previous head's readers
        // ---- QKV GEMM (transposed): D[col][token] = mfma(W^T-frag, X-frag) ----
#pragma unroll
        for (int rb = 0; rb < 2; ++rb) {
            const int t = wrow + rb * 16 + lr;          // token in this lane's column
            const int tsw = ((t >> 1) & 3) << 4;
#pragma unroll
            for (int ct = 0; ct < 6; ++ct) {
                const int sec = ct >> 1;
                const int colg = sec * 128 + h * 32 + (ct & 1) * 16 + lr;
                const __bf16* wp = qkvT + colg * 128;
                f32x4 c = (f32x4){0.f, 0.f, 0.f, 0.f};
#pragma unroll
                for (int kc = 0; kc < 4; ++kc) {
                    const bf16x8 wf = *reinterpret_cast<const bf16x8*>(wp + kc * 32 + hi * 8);
                    c = __builtin_amdgcn_mfma_f32_16x16x32_bf16(wf, Xf[rb][kc], c, 0, 0, 0);
                }
                // c[j] = value for (dloc = (ct&1)*16 + hi*4 + j, token t)
                if (sec == 0) {
                    bf16x4 pk;
#pragma unroll
                    for (int j = 0; j < 4; ++j) pk[j] = (__bf16)(c[j] * scale);
                    *reinterpret_cast<bf16x4*>(smem + QS_OFF + t * 64 +
                        (((ct & 1) * 32 + hi * 8) ^ tsw)) = pk;
                } else if (sec == 1) {
                    bf16x4 pk;
#pragma unroll
                    for (int j = 0; j < 4; ++j) pk[j] = (__bf16)c[j];
                    *reinterpret_cast<bf16x4*>(smem + KS_OFF + t * 64 +
                        (((ct & 1) * 32 + hi * 8) ^ tsw)) = pk;
                } else {
#pragma unroll
                    for (int j = 0; j < 4; ++j) {
                        const int d = (ct & 1) * 16 + hi * 4 + j;
                        *reinterpret_cast<__bf16*>(smem + VT_OFF + d * 512 +
                            ((t * 2) ^ ((d & 7) << 4))) = (__bf16)c[j];
                    }
                }
            }
        }
        __syncthreads();

        // ---- attention, fused S->exp->PV per 32-token k-chunk ----
#pragma unroll
        for (int rb = 0; rb < 2; ++rb) {
            const int rt = wave * 2 + rb;               // q-token tile index
            const int tq = wrow + rb * 16 + lr;
            const bf16x8 qf = *reinterpret_cast<const bf16x8*>(
                smem + QS_OFF + tq * 64 + ((hi * 16) ^ (((tq >> 1) & 3) << 4)));
            char* pb = smem + PB_OFF + wave * 1024;
            const int psw = ((lr >> 1) & 3) << 4;
            const float* bT = biasT + ((size_t)((h * 16) * 16 + rt) * 64 + lane) * 4;

            float lsum = 0.f;
            f32x4 O0 = (f32x4){0.f, 0.f, 0.f, 0.f};
            f32x4 O1 = (f32x4){0.f, 0.f, 0.f, 0.f};
#pragma unroll 2
            for (int kcc = 0; kcc < 8; ++kcc) {
#pragma unroll
                for (int tt = 0; tt < 2; ++tt) {
                    const int ct = kcc * 2 + tt;
                    const int tk = ct * 16 + lr;
                    const bf16x8 kf = *reinterpret_cast<const bf16x8*>(
                        smem + KS_OFF + tk * 64 + ((hi * 16) ^ (((tk >> 1) & 3) << 4)));
                    f32x4 s = __builtin_amdgcn_mfma_f32_16x16x32_bf16(
                        kf, qf, (f32x4){0.f, 0.f, 0.f, 0.f}, 0, 0, 0);
                    // s[j] = S[k = ct*16+hi*4+j][q = rt*16+lr]
                    const float4 bv = *reinterpret_cast<const float4*>(bT + ct * 4096);
                    s[0] += bv.x; s[1] += bv.y; s[2] += bv.z; s[3] += bv.w;
                    bf16x4 pk;
#pragma unroll
                    for (int j = 0; j < 4; ++j) {
                        const float p = __expf(s[j]);   // |S|<<1: no max-subtract needed
                        lsum += p;
                        pk[j] = (__bf16)p;
                    }
                    *reinterpret_cast<bf16x4*>(pb + lr * 64 + ((tt * 32 + hi * 8) ^ psw)) = pk;
                }
                const bf16x8 pf = *reinterpret_cast<const bf16x8*>(
                    pb + lr * 64 + ((hi * 16) ^ psw));
                const bf16x8 v0 = *reinterpret_cast<const bf16x8*>(
                    smem + VT_OFF + lr * 512 + ((kcc * 64 + hi * 16) ^ ((lr & 7) << 4)));
                const bf16x8 v1 = *reinterpret_cast<const bf16x8*>(
                    smem + VT_OFF + (16 + lr) * 512 + ((kcc * 64 + hi * 16) ^ ((lr & 7) << 4)));
                O0 = __builtin_amdgcn_mfma_f32_16x16x32_bf16(v0, pf, O0, 0, 0, 0);
                O1 = __builtin_amdgcn_mfma_f32_16x16x32_bf16(v1, pf, O1, 0, 0, 0);
            }
            lsum += __shfl_xor(lsum, 16, 64);
            lsum += __shfl_xor(lsum, 32, 64);
            const float rl = 1.f / lsum;

            bf16x4 oa, ob;
#pragma unroll
            for (int j = 0; j < 4; ++j) {
                oa[j] = (__bf16)(O0[j] * rl);
                ob[j] = (__bf16)(O1[j] * rl);
            }
            const size_t rp = ((size_t)b * NTOK + tq) * DIM + h * 32;
            *reinterpret_cast<bf16x4*>(O_ws + rp + hi * 4)      = oa;
            *reinterpret_cast<bf16x4*>(O_ws + rp + 16 + hi * 4) = ob;
        }
    }
}

// ---------------- proj GEMM kernel: out = O @ Wp + b ----------------
__global__ __launch_bounds__(256) void proj_kernel(
    const __bf16* __restrict__ O_ws, const __bf16* __restrict__ projT,
    const float* __restrict__ proj_b, float* __restrict__ out)
{
    const int tid = threadIdx.x;
    const int wave = tid >> 6, lane = tid & 63;
    const int lr = lane & 15, hi = lane >> 4;
    const int row0 = blockIdx.x * 128 + wave * 32;

#pragma unroll
    for (int rb = 0; rb < 2; ++rb) {
        const size_t t = (size_t)row0 + rb * 16 + lr;
        bf16x8 af[4];
#pragma unroll
        for (int kc = 0; kc < 4; ++kc)
            af[kc] = *reinterpret_cast<const bf16x8*>(O_ws + t * DIM + kc * 32 + hi * 8);
#pragma unroll
        for (int ct = 0; ct < 8; ++ct) {
            f32x4 a = (f32x4){0.f, 0.f, 0.f, 0.f};
#pragma unroll
            for (int kc = 0; kc < 4; ++kc) {
                const bf16x8 wpf = *reinterpret_cast<const bf16x8*>(
                    projT + (ct * 16 + lr) * 128 + kc * 32 + hi * 8);
                a = __builtin_amdgcn_mfma_f32_16x16x32_bf16(wpf, af[kc], a, 0, 0, 0);
            }
            const float4 pbv = *reinterpret_cast<const float4*>(proj_b + ct * 16 + hi * 4);
            f32x4 st;
            st[0] = a[0] + pbv.x; st[1] = a[1] + pbv.y;
            st[2] = a[2] + pbv.z; st[3] = a[3] + pbv.w;
            *reinterpret_cast<f32x4*>(out + t * DIM + ct * 16 + hi * 4) = st;
        }
    }
}

// ---------------- launcher ----------------

extern "C" void kernel_launch(void* const* d_in, const int* in_sizes, int n_in,
                              void* d_out, int out_size, void* d_ws, size_t ws_size,
                              hipStream_t stream)
{
    const float* x          = (const float*)d_in[0];
    const float* noise      = (const float*)d_in[1];
    const float* qkv_w      = (const float*)d_in[2];
    const float* proj_w     = (const float*)d_in[3];
    const float* proj_b     = (const float*)d_in[4];
    const float* bias_table = (const float*)d_in[5];
    const float* nstr       = (const float*)d_in[6];
    float* out = (float*)d_out;
    (void)in_sizes; (void)n_in; (void)out_size; (void)ws_size;

    char* ws = (char*)d_ws;
    const size_t OFF_BIAS  = 0;                                   // 1 MiB
    const size_t OFF_QKVT  = (size_t)1 << 20;                     // 96 KiB
    const size_t OFF_PROJT = OFF_QKVT + 384 * 128 * 2;            // 32 KiB
    const size_t OFF_O     = (size_t)2 << 20;                     // 64 MiB

    float*  biasT = (float*)(ws + OFF_BIAS);
    __bf16* qkvT  = (__bf16*)(ws + OFF_QKVT);
    __bf16* projT = (__bf16*)(ws + OFF_PROJT);
    __bf16* O_ws  = (__bf16*)(ws + OFF_O);

    bias_prep<<<256, 256, 0, stream>>>(bias_table, biasT);
    weight_prep<<<256, 256, 0, stream>>>(qkv_w, proj_w, qkvT, projT);

    hipFuncSetAttribute(reinterpret_cast<const void*>(attn_main),
                        hipFuncAttributeMaxDynamicSharedMemorySize, SMEM_BYTES);
    attn_main<<<1024, 512, SMEM_BYTES, stream>>>(x, noise, nstr, biasT, qkvT, O_ws);
    proj_kernel<<<2048, 256, 0, stream>>>(O_ws, projT, proj_b, out);
}